// Round 16
// baseline (226.995 us; speedup 1.0000x reference)
//
#include <hip/hip_runtime.h>
#include <math.h>

#define NB1 8192
#define NB2 12288
#define DD  128
#define NJB 96           // j-blocks (NB2/128)
#define NIB 64           // i-blocks (NB1/128)

typedef unsigned long long u64;
typedef unsigned short ushort_t;
typedef __attribute__((ext_vector_type(8))) short short8;
typedef __attribute__((ext_vector_type(8))) _Float16 half8;
typedef __attribute__((ext_vector_type(4))) float f32x4;

__device__ __forceinline__ float bigf() { return __uint_as_float(0x7F7F0000u); }
__device__ __forceinline__ u64 umin64(u64 a, u64 b) { return a < b ? a : b; }
__device__ __forceinline__ unsigned umin32(unsigned a, unsigned b) { return a < b ? a : b; }

__device__ __forceinline__ ushort_t bf_rn(float x) {
    unsigned u = __float_as_uint(x);
    return (ushort_t)((u + 0x7FFFu + ((u >> 16) & 1u)) >> 16);
}
__device__ __forceinline__ float bf_up(ushort_t h) {
    return __uint_as_float(((unsigned)h) << 16);
}
__device__ __forceinline__ int fswz(int r) { return (r + (r >> 2)) & 3; }
__device__ __forceinline__ half8 ld8h(const _Float16* p) { return *(const half8*)p; }

// Kernel N: squared norms + init packed min arrays (init only needed by the
// atomic fallback path; harmless otherwise).
__global__ __launch_bounds__(256) void prep_kernel(
    const float* __restrict__ d1, const float* __restrict__ d2,
    float* __restrict__ sq1, float* __restrict__ sq2,
    u64* __restrict__ rowmin, u64* __restrict__ colmin) {
    int t = blockIdx.x * 256 + threadIdx.x;
    if (t < NB1) {
        rowmin[t] = ~0ull;
        const float4* p = (const float4*)(d1 + (size_t)t * DD);
        float s = 0.f;
        #pragma unroll
        for (int c = 0; c < DD / 4; ++c) {
            float4 v = p[c];
            s = fmaf(v.x, v.x, s); s = fmaf(v.y, v.y, s);
            s = fmaf(v.z, v.z, s); s = fmaf(v.w, v.w, s);
        }
        sq1[t] = s;
    }
    if (t < NB2) {
        colmin[t] = ~0ull;
        const float4* p = (const float4*)(d2 + (size_t)t * DD);
        float s = 0.f;
        #pragma unroll
        for (int c = 0; c < DD / 4; ++c) {
            float4 v = p[c];
            s = fmaf(v.x, v.x, s); s = fmaf(v.y, v.y, s);
            s = fmaf(v.z, v.z, s); s = fmaf(v.w, v.w, s);
        }
        sq2[t] = s;
    }
}

// Kernel SE: 2-way f16 split into K-CONCATENATED fragment-major planes
// (round-13, verified). K_eff = 384 = 12 k-chunks of 32:
//   A' = [ H | M~ | H~ ]   B' = [ H' | H~' | M~' ]
// H = f16(x), m = x - H (exact), M~ = f16(2^8 m), H~ = f16(2^-8 H).
// GEMM over K=384 yields  Sum hh' + Sum mh' + Sum hm'  in ONE chain.
__global__ __launch_bounds__(256) void split_ext16_kernel(
    const float* __restrict__ d1, const float* __restrict__ d2,
    _Float16* __restrict__ Af, _Float16* __restrict__ Bf) {
    int t = blockIdx.x * 256 + threadIdx.x;    // 0 .. 983039
    int lane = t & 63;
    int task = t >> 6;                          // 0 .. 15359
    bool isA = task < 6144;
    int lt = isA ? task : task - 6144;
    int rb = lt / 12;
    int kc = lt - rb * 12;
    int region = kc >> 2;
    int row = rb * 16 + (lane & 15);
    int kst = (kc & 3) * 32 + (lane >> 4) * 8;
    const float* src = (isA ? d1 : d2) + (size_t)row * DD + kst;
    _Float16* dst = (isA ? Af : Bf) + ((size_t)lt * 512 + lane * 8);

    bool wantM = isA ? (region == 1) : (region == 2);
    half8 V;
    #pragma unroll
    for (int e = 0; e < 8; ++e) {
        float x = src[e];
        _Float16 hf = (_Float16)x;
        float h = (float)hf;
        float v;
        if (region == 0)      v = x;
        else if (wantM)       v = (x - h) * 256.0f;
        else                  v = h * 0.00390625f;
        V[e] = (_Float16)v;
    }
    *(half8*)dst = V;
}

// Kernel T10: round-13 barrier-free f16 MFMA loop + ATOMIC-FREE epilogue.
// Per-block candidates are merged across the wc/wr duplicate waves in LDS,
// then stored with plain coalesced u64 writes into private partial arrays
// (each slot written by exactly ONE block -> zero contention). The previous
// device-scope atomicMin stream (~3.1M lane-RMWs on 160 KB) is the prime
// suspect for the ~200 us floor; this removes it entirely.
__global__ __launch_bounds__(256) void mfma_tile10_kernel(
    const _Float16* __restrict__ Af, const _Float16* __restrict__ Bf,
    const float* __restrict__ sq1, const float* __restrict__ sq2,
    u64* __restrict__ rowpart, u64* __restrict__ colpart)
{
    __shared__ u64 rowbuf[2][128];   // [wc][block row]
    __shared__ u64 colbuf[2][128];   // [wr][block col]

    const int bid  = blockIdx.x;
    const int xcd  = bid & 7;
    const int t_   = bid >> 3;
    const int kch  = t_ >> 6;
    const int wdn  = t_ & 63;
    const int j0b  = (kch * 8 + (wdn & 7)) * 128;
    const int i0b  = (xcd * 8 + (wdn >> 3)) * 128;

    const int tid  = threadIdx.x;
    const int lane = tid & 63;
    const int wid  = tid >> 6;
    const int wr   = wid >> 1;
    const int wc   = wid & 1;
    const int lrow = lane & 15;
    const int lg   = lane >> 4;

    const _Float16* abase = Af + ((size_t)((i0b >> 4) + wr * 4) * 6144) + lane * 8;
    const _Float16* bbase = Bf + ((size_t)((j0b >> 4) + wc * 4) * 6144) + lane * 8;

    f32x4 acc[4][4];
    #pragma unroll
    for (int mi = 0; mi < 4; ++mi)
        #pragma unroll
        for (int ni = 0; ni < 4; ++ni)
            acc[mi][ni] = (f32x4){0.f, 0.f, 0.f, 0.f};

    #pragma unroll 1
    for (int kc = 0; kc < 12; ++kc) {
        const int ko = kc * 512;
        half8 bfr[4];
        #pragma unroll
        for (int ni = 0; ni < 4; ++ni)
            bfr[ni] = ld8h(bbase + ni * 6144 + ko);
        half8 a0, a1;
        a0 = ld8h(abase + ko);
        #pragma unroll
        for (int mi = 0; mi < 4; ++mi) {
            if (mi < 3)
                a1 = ld8h(abase + (mi + 1) * 6144 + ko);
            #pragma unroll
            for (int ni = 0; ni < 4; ++ni)
                acc[mi][ni] = __builtin_amdgcn_mfma_f32_16x16x32_f16(a0, bfr[ni], acc[mi][ni], 0, 0, 0);
            a0 = a1;
        }
    }

    // ---- epilogue: tracked argmin -> LDS merge -> private partial stores.
    float q2v[4];
    #pragma unroll
    for (int ni = 0; ni < 4; ++ni)
        q2v[ni] = sq2[j0b + wc * 64 + ni * 16 + lrow];
    float4 q1v[4];
    #pragma unroll
    for (int mi = 0; mi < 4; ++mi)
        q1v[mi] = *(const float4*)(sq1 + i0b + wr * 64 + mi * 16 + 4 * lg);

    float    cmin[4];
    unsigned cidx[4];
    #pragma unroll
    for (int ni = 0; ni < 4; ++ni) { cmin[ni] = __uint_as_float(0x7F800000u); cidx[ni] = 0xFFFFFFFFu; }

    #pragma unroll
    for (int mi = 0; mi < 4; ++mi) {
        const float* q1p = (const float*)&q1v[mi];
        #pragma unroll
        for (int r = 0; r < 4; ++r) {
            const float    q1 = q1p[r];
            const unsigned irow = (unsigned)(i0b + wr * 64 + mi * 16 + 4 * lg + r);
            float    rbest = 0.f;
            unsigned rbn = 0;
            #pragma unroll
            for (int ni = 0; ni < 4; ++ni) {
                float d = acc[mi][ni][r];
                float t = fmaf(-2.f, d, q2v[ni]);
                float c = fmaf(-2.f, d, q1);
                if (ni == 0) { rbest = t; }
                else if (t < rbest) { rbest = t; rbn = (unsigned)ni; }
                if (c < cmin[ni]) { cmin[ni] = c; cidx[ni] = irow; }
            }
            float g = rbest;
            #pragma unroll
            for (int mask = 8; mask; mask >>= 1)
                g = fminf(g, __shfl_xor(g, mask));
            unsigned jc = (rbest == g)
                ? (unsigned)(j0b + wc * 64 + rbn * 16 + lrow) : 0xFFFFFFFFu;
            #pragma unroll
            for (int mask = 8; mask; mask >>= 1)
                jc = umin32(jc, (unsigned)__shfl_xor((int)jc, mask));
            if (lrow == 0) {
                float d2 = g + q1;                      // dist^2 >= 0
                rowbuf[wc][wr * 64 + mi * 16 + 4 * lg + r] =
                    ((u64)__float_as_uint(d2) << 32) | jc;
            }
        }
    }
    #pragma unroll
    for (int ni = 0; ni < 4; ++ni) {
        float d2 = cmin[ni] + q2v[ni];
        u64 pk = ((u64)__float_as_uint(d2) << 32) | cidx[ni];
        pk = umin64(pk, __shfl_xor(pk, 16));
        pk = umin64(pk, __shfl_xor(pk, 32));
        if (lane < 16)
            colbuf[wr][wc * 64 + ni * 16 + lrow] = pk;
    }
    __syncthreads();

    // Merge wc/wr duplicates; plain coalesced stores (unique slot per block).
    const int jb = j0b >> 7;
    const int ib = i0b >> 7;
    if (tid < 128) {
        u64 pk = umin64(rowbuf[0][tid], rowbuf[1][tid]);
        rowpart[(size_t)jb * NB1 + i0b + tid] = pk;
    } else {
        int c = tid - 128;
        u64 pk = umin64(colbuf[0][c], colbuf[1][c]);
        colpart[(size_t)ib * NB2 + j0b + c] = pk;
    }
}

// Kernel R: reduce partials -> rowmin / colmin (coalesced across threads).
__global__ __launch_bounds__(256) void reduce_kernel(
    const u64* __restrict__ rowpart, const u64* __restrict__ colpart,
    u64* __restrict__ rowmin, u64* __restrict__ colmin) {
    int t = blockIdx.x * 256 + threadIdx.x;
    if (t < NB1) {
        u64 m = ~0ull;
        #pragma unroll 8
        for (int jb = 0; jb < NJB; ++jb)
            m = umin64(m, rowpart[(size_t)jb * NB1 + t]);
        rowmin[t] = m;
    } else if (t < NB1 + NB2) {
        int j = t - NB1;
        u64 m = ~0ull;
        #pragma unroll 8
        for (int ib = 0; ib < NIB; ++ib)
            m = umin64(m, colpart[(size_t)ib * NB2 + j]);
        colmin[j] = m;
    }
}

// ============================ fallback path ============================
// In-kernel bf16 3-way split LDS version with atomics; dist^2-bit packing.
__global__ __launch_bounds__(256) void mfma_tile_kernel(
    const float* __restrict__ d1, const float* __restrict__ d2,
    const float* __restrict__ sq1, const float* __restrict__ sq2,
    u64* __restrict__ rowmin, u64* __restrict__ colmin)
{
    __shared__ __align__(16) short lds[6 * 4096];
    const int tid = threadIdx.x;
    const int i0b = blockIdx.y * 128;
    const int j0b = blockIdx.x * 128;
    const int srow  = tid >> 1;
    const int shalf = tid & 1;
    const int sfr   = fswz(srow);
    const int sg0   = ((2 * shalf) ^ sfr) * 8;
    const int sg1   = ((2 * shalf + 1) ^ sfr) * 8;
    const float* gA = d1 + (size_t)(i0b + srow) * DD + shalf * 16;
    const float* gB = d2 + (size_t)(j0b + srow) * DD + shalf * 16;
    short* wA = lds + srow * 32;
    short* wB = lds + 3 * 4096 + srow * 32;
    const int lane = tid & 63;
    const int wid  = tid >> 6;
    const int wr   = wid >> 1;
    const int wc   = wid & 1;
    const int lrow = lane & 15;
    const int lg   = lane >> 4;
    const int gx   = (lg ^ fswz(lrow)) * 8;
    const int aoff = (wr * 64 + lrow) * 32 + gx;
    const int boff = 3 * 4096 + (wc * 64 + lrow) * 32 + gx;

    f32x4 acc[4][4];
    #pragma unroll
    for (int mi = 0; mi < 4; ++mi)
        #pragma unroll
        for (int ni = 0; ni < 4; ++ni)
            acc[mi][ni] = (f32x4){0.f, 0.f, 0.f, 0.f};

    for (int kc = 0; kc < 4; ++kc) {
        {
            const float* sp = gA + kc * 32;
            short8 H0, M0, L0, H1, M1, L1;
            #pragma unroll
            for (int e = 0; e < 8; ++e) {
                float x = sp[e];
                ushort_t h = bf_rn(x); float r1 = x - bf_up(h);
                ushort_t m = bf_rn(r1); float r2 = r1 - bf_up(m);
                H0[e] = (short)h; M0[e] = (short)m; L0[e] = (short)bf_rn(r2);
            }
            #pragma unroll
            for (int e = 0; e < 8; ++e) {
                float x = sp[8 + e];
                ushort_t h = bf_rn(x); float r1 = x - bf_up(h);
                ushort_t m = bf_rn(r1); float r2 = r1 - bf_up(m);
                H1[e] = (short)h; M1[e] = (short)m; L1[e] = (short)bf_rn(r2);
            }
            *(short8*)(wA + sg0)        = H0;
            *(short8*)(wA + sg1)        = H1;
            *(short8*)(wA + 4096 + sg0) = M0;
            *(short8*)(wA + 4096 + sg1) = M1;
            *(short8*)(wA + 8192 + sg0) = L0;
            *(short8*)(wA + 8192 + sg1) = L1;
        }
        {
            const float* sp = gB + kc * 32;
            short8 H0, M0, L0, H1, M1, L1;
            #pragma unroll
            for (int e = 0; e < 8; ++e) {
                float x = sp[e];
                ushort_t h = bf_rn(x); float r1 = x - bf_up(h);
                ushort_t m = bf_rn(r1); float r2 = r1 - bf_up(m);
                H0[e] = (short)h; M0[e] = (short)m; L0[e] = (short)bf_rn(r2);
            }
            #pragma unroll
            for (int e = 0; e < 8; ++e) {
                float x = sp[8 + e];
                ushort_t h = bf_rn(x); float r1 = x - bf_up(h);
                ushort_t m = bf_rn(r1); float r2 = r1 - bf_up(m);
                H1[e] = (short)h; M1[e] = (short)m; L1[e] = (short)bf_rn(r2);
            }
            *(short8*)(wB + sg0)        = H0;
            *(short8*)(wB + sg1)        = H1;
            *(short8*)(wB + 4096 + sg0) = M0;
            *(short8*)(wB + 4096 + sg1) = M1;
            *(short8*)(wB + 8192 + sg0) = L0;
            *(short8*)(wB + 8192 + sg1) = L1;
        }
        __syncthreads();
        short8 af[3][4], bfr[3][4];
        #pragma unroll
        for (int c = 0; c < 3; ++c)
            #pragma unroll
            for (int t = 0; t < 4; ++t) {
                af[c][t]  = *(const short8*)(lds + c * 4096 + aoff + t * 512);
                bfr[c][t] = *(const short8*)(lds + c * 4096 + boff + t * 512);
            }
        #pragma unroll
        for (int mi = 0; mi < 4; ++mi)
            #pragma unroll
            for (int ni = 0; ni < 4; ++ni) {
                f32x4 a = acc[mi][ni];
                a = __builtin_amdgcn_mfma_f32_16x16x32_bf16(af[0][mi], bfr[0][ni], a, 0, 0, 0);
                a = __builtin_amdgcn_mfma_f32_16x16x32_bf16(af[0][mi], bfr[1][ni], a, 0, 0, 0);
                a = __builtin_amdgcn_mfma_f32_16x16x32_bf16(af[1][mi], bfr[0][ni], a, 0, 0, 0);
                a = __builtin_amdgcn_mfma_f32_16x16x32_bf16(af[0][mi], bfr[2][ni], a, 0, 0, 0);
                a = __builtin_amdgcn_mfma_f32_16x16x32_bf16(af[1][mi], bfr[1][ni], a, 0, 0, 0);
                a = __builtin_amdgcn_mfma_f32_16x16x32_bf16(af[2][mi], bfr[0][ni], a, 0, 0, 0);
                acc[mi][ni] = a;
            }
        __syncthreads();
    }

    float q2v[4];
    #pragma unroll
    for (int ni = 0; ni < 4; ++ni)
        q2v[ni] = sq2[j0b + wc * 64 + ni * 16 + lrow];
    float4 q1v[4];
    #pragma unroll
    for (int mi = 0; mi < 4; ++mi)
        q1v[mi] = *(const float4*)(sq1 + i0b + wr * 64 + mi * 16 + 4 * lg);

    float    cmin[4];
    unsigned cidx[4];
    #pragma unroll
    for (int ni = 0; ni < 4; ++ni) { cmin[ni] = __uint_as_float(0x7F800000u); cidx[ni] = 0xFFFFFFFFu; }

    #pragma unroll
    for (int mi = 0; mi < 4; ++mi) {
        const float* q1p = (const float*)&q1v[mi];
        #pragma unroll
        for (int r = 0; r < 4; ++r) {
            const float    q1 = q1p[r];
            const unsigned irow = (unsigned)(i0b + wr * 64 + mi * 16 + 4 * lg + r);
            float    rbest = 0.f;
            unsigned rbn = 0;
            #pragma unroll
            for (int ni = 0; ni < 4; ++ni) {
                float d = acc[mi][ni][r];
                float t = fmaf(-2.f, d, q2v[ni]);
                float c = fmaf(-2.f, d, q1);
                if (ni == 0) { rbest = t; }
                else if (t < rbest) { rbest = t; rbn = (unsigned)ni; }
                if (c < cmin[ni]) { cmin[ni] = c; cidx[ni] = irow; }
            }
            float g = rbest;
            #pragma unroll
            for (int mask = 8; mask; mask >>= 1)
                g = fminf(g, __shfl_xor(g, mask));
            unsigned jc = (rbest == g)
                ? (unsigned)(j0b + wc * 64 + rbn * 16 + lrow) : 0xFFFFFFFFu;
            #pragma unroll
            for (int mask = 8; mask; mask >>= 1)
                jc = umin32(jc, (unsigned)__shfl_xor((int)jc, mask));
            if (lrow == 0) {
                float d2 = g + q1;
                u64 pk = ((u64)__float_as_uint(d2) << 32) | jc;
                atomicMin(&rowmin[irow], pk);
            }
        }
    }
    #pragma unroll
    for (int ni = 0; ni < 4; ++ni) {
        float d2 = cmin[ni] + q2v[ni];
        u64 pk = ((u64)__float_as_uint(d2) << 32) | cidx[ni];
        pk = umin64(pk, __shfl_xor(pk, 16));
        pk = umin64(pk, __shfl_xor(pk, 32));
        if (lane < 16)
            atomicMin(&colmin[j0b + wc * 64 + ni * 16 + lrow], pk);
    }
}

// Kernel 3: assemble outputs. rowmin/colmin hold (dist^2 bits << 32) | idx.
// Non-mutual rows get bigf() instead of +inf (inf-inf = NaN fails diff).
__global__ __launch_bounds__(256) void final_kernel(
    const u64* __restrict__ rowmin, const u64* __restrict__ colmin,
    float* __restrict__ out) {
    int i = blockIdx.x * 256 + threadIdx.x;
    if (i >= NB1) return;
    u64 rm = rowmin[i];
    unsigned ju = (unsigned)(rm & 0xFFFFFFFFu);
    float d2 = __uint_as_float((unsigned)(rm >> 32));
    float dist = sqrtf(fmaxf(d2, 0.f));
    dist = fminf(dist, bigf());
    bool valid = (ju < (unsigned)NB2);
    int j = valid ? (int)ju : 0;
    u64 cm = colmin[j];
    int i2 = (int)(cm & 0xFFFFFFFFu);
    bool mut = valid && (i2 == i);
    out[i] = mut ? dist : bigf();
    out[NB1 + 2 * i]     = mut ? (float)i : -1.f;
    out[NB1 + 2 * i + 1] = mut ? (float)j : -1.f;
    out[NB1 + 2 * NB1 + i] = mut ? 1.f : 0.f;
}

extern "C" void kernel_launch(void* const* d_in, const int* in_sizes, int n_in,
                              void* d_out, int out_size, void* d_ws, size_t ws_size,
                              hipStream_t stream) {
    const float* d1 = (const float*)d_in[0];
    const float* d2 = (const float*)d_in[1];
    float* out = (float*)d_out;

    char* ws = (char*)d_ws;
    float* sq1    = (float*)(ws);
    float* sq2    = (float*)(ws + 32768);
    u64*   rowmin = (u64*)(ws + 81920);
    u64*   colmin = (u64*)(ws + 147456);
    _Float16* Af = (_Float16*)(ws + 245760);             // 6,291,456 B
    _Float16* Bf = (_Float16*)(ws + 245760 + 6291456);   // 9,437,184 B
    u64* rowpart = (u64*)(ws + 15974400);                // 96*8192*8  = 6,291,456 B
    u64* colpart = (u64*)(ws + 15974400 + 6291456);      // 64*12288*8 = 6,291,456 B
    const size_t need2 = 15974400 + 2 * 6291456;         // ~28.6 MB
    const size_t need1 = 245760 + 6291456 + 9437184;     // ~15.2 MB

    hipLaunchKernelGGL(prep_kernel, dim3((NB2 + 255) / 256), dim3(256), 0, stream,
                       d1, d2, sq1, sq2, rowmin, colmin);
    if (ws_size >= need2) {
        hipLaunchKernelGGL(split_ext16_kernel, dim3(3840), dim3(256), 0, stream,
                           d1, d2, Af, Bf);
        hipLaunchKernelGGL(mfma_tile10_kernel, dim3(6144), dim3(256), 0, stream,
                           Af, Bf, sq1, sq2, rowpart, colpart);
        hipLaunchKernelGGL(reduce_kernel, dim3((NB1 + NB2 + 255) / 256), dim3(256), 0, stream,
                           rowpart, colpart, rowmin, colmin);
    } else if (ws_size >= need1) {
        hipLaunchKernelGGL(split_ext16_kernel, dim3(3840), dim3(256), 0, stream,
                           d1, d2, Af, Bf);
        // No room for partials: fall back to the bf16 atomic LDS kernel.
        hipLaunchKernelGGL(mfma_tile_kernel, dim3(NB2 / 128, NB1 / 128), dim3(256), 0, stream,
                           d1, d2, sq1, sq2, rowmin, colmin);
    } else {
        hipLaunchKernelGGL(mfma_tile_kernel, dim3(NB2 / 128, NB1 / 128), dim3(256), 0, stream,
                           d1, d2, sq1, sq2, rowmin, colmin);
    }
    hipLaunchKernelGGL(final_kernel, dim3((NB1 + 255) / 256), dim3(256), 0, stream,
                       rowmin, colmin, out);
}